// Round 1
// baseline (607.113 us; speedup 1.0000x reference)
//
#include <hip/hip_runtime.h>

// SparseLinear == dense GEMM: C[M,N] = A[M,K] @ B[K,N] + bias[N]
// A = x (f32), B = weight as stored (row-major, indexed [i][o]), all f32 in/out.
// Strategy: pre-pass converts A->bf16 and B->B^T bf16 in d_ws, then m97-style
// 128x128 bf16 MFMA GEMM (global_load_lds width=16, BK=32, 2-barrier K-loop).

#define MDIM 8192
#define NDIM 4096
#define KDIM 4096
#define BM 128
#define BN 128
#define BK 32

typedef __bf16 bf16x8 __attribute__((ext_vector_type(8)));
typedef float f32x4 __attribute__((ext_vector_type(4)));

__device__ __forceinline__ unsigned short f32_to_bf16(float f) {
  union { float f; unsigned int u; } v; v.f = f;
  unsigned int r = 0x7FFFu + ((v.u >> 16) & 1u);  // round-to-nearest-even
  return (unsigned short)((v.u + r) >> 16);
}

// ---- x (f32) -> bf16, 8 elems/thread -------------------------------------
__global__ __launch_bounds__(256) void cvt_bf16_kernel(
    const float* __restrict__ src, unsigned short* __restrict__ dst, int n) {
  int i = (blockIdx.x * 256 + threadIdx.x) * 8;
  if (i >= n) return;
  float4 a = *(const float4*)(src + i);
  float4 b = *(const float4*)(src + i + 4);
  union { unsigned short s[8]; uint4 v; } o;
  o.s[0] = f32_to_bf16(a.x); o.s[1] = f32_to_bf16(a.y);
  o.s[2] = f32_to_bf16(a.z); o.s[3] = f32_to_bf16(a.w);
  o.s[4] = f32_to_bf16(b.x); o.s[5] = f32_to_bf16(b.y);
  o.s[6] = f32_to_bf16(b.z); o.s[7] = f32_to_bf16(b.w);
  *(uint4*)(dst + i) = o.v;
}

// ---- W (KxN f32 row-major) -> Wt (NxK bf16 row-major), tiled transpose ----
__global__ __launch_bounds__(256) void transpose_cvt_kernel(
    const float* __restrict__ W, unsigned short* __restrict__ Wt) {
  __shared__ unsigned short tile[32][34];  // pad 34 (17 banks stride, odd) -> conflict-free
  const int n0 = blockIdx.x * 32;
  const int k0 = blockIdx.y * 32;
  const int tx = threadIdx.x & 31;
  const int ty = threadIdx.x >> 5;  // 0..7
#pragma unroll
  for (int i = 0; i < 4; i++) {
    int kl = ty + i * 8;
    tile[kl][tx] = f32_to_bf16(W[(k0 + kl) * NDIM + n0 + tx]);
  }
  __syncthreads();
#pragma unroll
  for (int i = 0; i < 4; i++) {
    int nl = ty + i * 8;
    Wt[(n0 + nl) * KDIM + k0 + tx] = tile[tx][nl];
  }
}

// ---- GEMM: C = A(bf16, MxK) * Bt(bf16, NxK)^T + bias, f32 out ------------
#define GLD_TO_LDS(g, l)                                                      \
  __builtin_amdgcn_global_load_lds(                                           \
      (const __attribute__((address_space(1))) void*)(g),                     \
      (__attribute__((address_space(3))) void*)(l), 16, 0, 0)

__global__ __launch_bounds__(256) void gemm_bf16_kernel(
    const unsigned short* __restrict__ A,   // M x K bf16
    const unsigned short* __restrict__ Bt,  // N x K bf16
    const float* __restrict__ bias,
    float* __restrict__ C) {
  // LDS tiles, lane-contiguous (NO padding: global_load_lds dest = base+lane*16)
  __shared__ __align__(16) unsigned short As[BM * BK];  // 8 KB, row-major [m][k]
  __shared__ __align__(16) unsigned short Bs[BN * BK];  // 8 KB, row-major [n][k]

  const int tid  = threadIdx.x;
  const int wave = tid >> 6;
  const int lane = tid & 63;
  const int lr   = lane & 15;
  const int quad = lane >> 4;

  const int bm0 = blockIdx.y * BM;
  const int bn0 = blockIdx.x * BN;

  // Staging: per wave 2 instrs x 1KB; instr covers 16 rows x 32 bf16.
  // lane -> row = instrBase*16 + lane/4, col = (lane%4)*8 ; LDS = base + lane*16
  const int stRow = wave * 32 + (lane >> 2);
  const int stCol = (lane & 3) * 8;
  const unsigned short* gA0 = A  + (bm0 + stRow) * KDIM + stCol;
  const unsigned short* gA1 = gA0 + 16 * KDIM;
  const unsigned short* gB0 = Bt + (bn0 + stRow) * KDIM + stCol;
  const unsigned short* gB1 = gB0 + 16 * KDIM;
  unsigned short* lA0 = As + wave * 1024;
  unsigned short* lA1 = As + wave * 1024 + 512;
  unsigned short* lB0 = Bs + wave * 1024;
  unsigned short* lB1 = Bs + wave * 1024 + 512;

  // Wave computes 64x64: wm/wn in 2x2 arrangement; 4x4 frags of 16x16.
  const int wm = (wave >> 1) * 64;
  const int wn = (wave & 1) * 64;
  // A-frag: A[m = lr][k = quad*8 + j]; B-frag mirrors with n = lr.
  const unsigned short* aAddr = As + (wm + lr) * BK + quad * 8;
  const unsigned short* bAddr = Bs + (wn + lr) * BK + quad * 8;

  f32x4 acc[4][4] = {};

  for (int k0 = 0; k0 < KDIM; k0 += BK) {
    GLD_TO_LDS(gA0, lA0);
    GLD_TO_LDS(gA1, lA1);
    GLD_TO_LDS(gB0, lB0);
    GLD_TO_LDS(gB1, lB1);
    gA0 += BK; gA1 += BK; gB0 += BK; gB1 += BK;
    __syncthreads();  // drains vmcnt -> LDS writes visible

    bf16x8 af[4], bfv[4];
#pragma unroll
    for (int i = 0; i < 4; i++) {
      af[i]  = *(const bf16x8*)(aAddr + i * 16 * BK);
      bfv[i] = *(const bf16x8*)(bAddr + i * 16 * BK);
    }
#pragma unroll
    for (int mi = 0; mi < 4; mi++)
#pragma unroll
      for (int ni = 0; ni < 4; ni++)
        acc[mi][ni] = __builtin_amdgcn_mfma_f32_16x16x32_bf16(
            af[mi], bfv[ni], acc[mi][ni], 0, 0, 0);
    __syncthreads();  // all reads done before next stage overwrites LDS
  }

  // Epilogue: C/D layout col = lane&15, row = quad*4 + reg  [m89/m91]
  const int om = bm0 + wm + quad * 4;
  const int on = bn0 + wn + lr;
#pragma unroll
  for (int ni = 0; ni < 4; ni++) {
    float bv = bias[on + ni * 16];
#pragma unroll
    for (int mi = 0; mi < 4; mi++) {
      f32x4 v = acc[mi][ni];
#pragma unroll
      for (int r = 0; r < 4; r++) {
        C[(om + mi * 16 + r) * NDIM + (on + ni * 16)] = v[r] + bv;
      }
    }
  }
}

extern "C" void kernel_launch(void* const* d_in, const int* in_sizes, int n_in,
                              void* d_out, int out_size, void* d_ws, size_t ws_size,
                              hipStream_t stream) {
  const float* x    = (const float*)d_in[0];  // 8192 x 4096
  const float* w    = (const float*)d_in[1];  // 4096 x 4096 (row-major [i][o])
  const float* bias = (const float*)d_in[2];  // 4096
  float* out = (float*)d_out;

  unsigned short* Xbf = (unsigned short*)d_ws;                         // 64 MB
  unsigned short* Wt  = (unsigned short*)((char*)d_ws + (size_t)MDIM * KDIM * 2);  // 32 MB

  // 1) x -> bf16 (33.5M elems, 8/thread)
  cvt_bf16_kernel<<<(MDIM * KDIM) / (8 * 256), 256, 0, stream>>>(x, Xbf, MDIM * KDIM);
  // 2) W -> W^T bf16
  transpose_cvt_kernel<<<dim3(NDIM / 32, KDIM / 32), 256, 0, stream>>>(w, Wt);
  // 3) GEMM + bias
  gemm_bf16_kernel<<<dim3(NDIM / BN, MDIM / BM), 256, 0, stream>>>(Xbf, Wt, bias, out);
}

// Round 2
// 599.511 us; speedup vs baseline: 1.0127x; 1.0127x over previous
//
#include <hip/hip_runtime.h>

// Dense GEMM: C[M,N] = x[M,K] @ W[K,N] + bias[N], f32 in/out, bf16 MFMA compute.
// R2: (a) XOR-swizzled LDS layout (kills 8-way ds_read_b128 bank conflicts),
//     (b) LDS-free vectorized transpose pre-pass.

#define MDIM 8192
#define NDIM 4096
#define KDIM 4096
#define BM 128
#define BN 128
#define BK 32

typedef __bf16 bf16x8 __attribute__((ext_vector_type(8)));
typedef float f32x4 __attribute__((ext_vector_type(4)));
typedef unsigned short u16x8 __attribute__((ext_vector_type(8)));

__device__ __forceinline__ unsigned short f32_to_bf16(float f) {
  union { float f; unsigned int u; } v; v.f = f;
  unsigned int r = 0x7FFFu + ((v.u >> 16) & 1u);  // round-to-nearest-even
  return (unsigned short)((v.u + r) >> 16);
}

// ---- x (f32) -> bf16, 8 elems/thread -------------------------------------
__global__ __launch_bounds__(256) void cvt_bf16_kernel(
    const float* __restrict__ src, unsigned short* __restrict__ dst, int n) {
  int i = (blockIdx.x * 256 + threadIdx.x) * 8;
  if (i >= n) return;
  float4 a = *(const float4*)(src + i);
  float4 b = *(const float4*)(src + i + 4);
  union { unsigned short s[8]; uint4 v; } o;
  o.s[0] = f32_to_bf16(a.x); o.s[1] = f32_to_bf16(a.y);
  o.s[2] = f32_to_bf16(a.z); o.s[3] = f32_to_bf16(a.w);
  o.s[4] = f32_to_bf16(b.x); o.s[5] = f32_to_bf16(b.y);
  o.s[6] = f32_to_bf16(b.z); o.s[7] = f32_to_bf16(b.w);
  *(uint4*)(dst + i) = o.v;
}

// ---- W (KxN f32) -> Wt (NxK bf16), LDS-free ------------------------------
// Block = 256 threads covers 64 n x 32 k. Thread: n = n0 + (tid&63),
// kbase = k0 + (tid>>6)*8. 8 reads of W[kbase+j][n] are each 64 consecutive
// floats per wave (256B coalesced); one ushort8 store (1KB/wave contiguous).
__global__ __launch_bounds__(256) void transpose_cvt_kernel(
    const float* __restrict__ W, unsigned short* __restrict__ Wt) {
  const int n = blockIdx.x * 64 + (threadIdx.x & 63);
  const int kbase = blockIdx.y * 32 + (threadIdx.x >> 6) * 8;
  u16x8 o;
#pragma unroll
  for (int j = 0; j < 8; j++)
    o[j] = f32_to_bf16(W[(size_t)(kbase + j) * NDIM + n]);
  *(u16x8*)(Wt + (size_t)n * KDIM + kbase) = o;
}

// ---- GEMM: C = A(bf16, MxK) * Bt(bf16, NxK)^T + bias, f32 out ------------
#define GLD_TO_LDS(g, l)                                                      \
  __builtin_amdgcn_global_load_lds(                                           \
      (const __attribute__((address_space(1))) void*)(g),                     \
      (__attribute__((address_space(3))) void*)(l), 16, 0, 0)

__global__ __launch_bounds__(256) void gemm_bf16_kernel(
    const unsigned short* __restrict__ A,   // M x K bf16
    const unsigned short* __restrict__ Bt,  // N x K bf16
    const float* __restrict__ bias,
    float* __restrict__ C) {
  // LDS tiles. Layout: row r (of 128), 4 segments of 8 bf16. Segment slot s'
  // holds global k-segment s = s' ^ ((r>>1)&3)  [XOR swizzle -> 2-way banks].
  __shared__ __align__(16) unsigned short As[BM * BK];  // 8 KB
  __shared__ __align__(16) unsigned short Bs[BN * BK];  // 8 KB

  const int tid  = threadIdx.x;
  const int wave = tid >> 6;
  const int lane = tid & 63;
  const int lr   = lane & 15;
  const int quad = lane >> 4;

  const int bm0 = blockIdx.y * BM;
  const int bn0 = blockIdx.x * BN;

  // Staging: lane's LDS slot = (row r = lane>>2, seg slot s' = lane&3).
  // It must fetch global segment s = s' ^ ((r>>1)&3); (r>>1)&3 == (lane>>3)&3.
  const int stRow = wave * 32 + (lane >> 2);
  const int stCol = (((lane & 3) ^ ((lane >> 3) & 3))) * 8;
  const unsigned short* gA0 = A  + (size_t)(bm0 + stRow) * KDIM + stCol;
  const unsigned short* gA1 = gA0 + 16 * KDIM;
  const unsigned short* gB0 = Bt + (size_t)(bn0 + stRow) * KDIM + stCol;
  const unsigned short* gB1 = gB0 + 16 * KDIM;
  unsigned short* lA0 = As + wave * 1024;
  unsigned short* lA1 = As + wave * 1024 + 512;
  unsigned short* lB0 = Bs + wave * 1024;
  unsigned short* lB1 = Bs + wave * 1024 + 512;

  // Wave computes 64x64: 4x4 frags of 16x16x32.
  const int wm = (wave >> 1) * 64;
  const int wn = (wave & 1) * 64;
  // Read swizzle: seg = quad ^ ((row>>1)&3); row = wm+lr, wm%64==0 and the
  // +16i frag offsets don't change (row>>1)&3 -> one address for all frags.
  const int aSeg = (quad ^ ((lr >> 1) & 3)) * 8;
  const unsigned short* aAddr = As + (wm + lr) * BK + aSeg;
  const unsigned short* bAddr = Bs + (wn + lr) * BK + aSeg;

  f32x4 acc[4][4] = {};

  for (int k0 = 0; k0 < KDIM; k0 += BK) {
    GLD_TO_LDS(gA0, lA0);
    GLD_TO_LDS(gA1, lA1);
    GLD_TO_LDS(gB0, lB0);
    GLD_TO_LDS(gB1, lB1);
    gA0 += BK; gA1 += BK; gB0 += BK; gB1 += BK;
    __syncthreads();

    bf16x8 af[4], bfv[4];
#pragma unroll
    for (int i = 0; i < 4; i++) {
      af[i]  = *(const bf16x8*)(aAddr + i * 16 * BK);
      bfv[i] = *(const bf16x8*)(bAddr + i * 16 * BK);
    }
#pragma unroll
    for (int mi = 0; mi < 4; mi++)
#pragma unroll
      for (int ni = 0; ni < 4; ni++)
        acc[mi][ni] = __builtin_amdgcn_mfma_f32_16x16x32_bf16(
            af[mi], bfv[ni], acc[mi][ni], 0, 0, 0);
    __syncthreads();
  }

  // Epilogue: C/D layout col = lane&15, row = quad*4 + reg  [m89/m91]
  const int om = bm0 + wm + quad * 4;
  const int on = bn0 + wn + lr;
#pragma unroll
  for (int ni = 0; ni < 4; ni++) {
    float bv = bias[on + ni * 16];
#pragma unroll
    for (int mi = 0; mi < 4; mi++) {
      f32x4 v = acc[mi][ni];
#pragma unroll
      for (int r = 0; r < 4; r++) {
        C[(size_t)(om + mi * 16 + r) * NDIM + (on + ni * 16)] = v[r] + bv;
      }
    }
  }
}

extern "C" void kernel_launch(void* const* d_in, const int* in_sizes, int n_in,
                              void* d_out, int out_size, void* d_ws, size_t ws_size,
                              hipStream_t stream) {
  const float* x    = (const float*)d_in[0];  // 8192 x 4096
  const float* w    = (const float*)d_in[1];  // 4096 x 4096 ([k][n])
  const float* bias = (const float*)d_in[2];  // 4096
  float* out = (float*)d_out;

  unsigned short* Xbf = (unsigned short*)d_ws;  // 64 MB
  unsigned short* Wt  = (unsigned short*)((char*)d_ws + (size_t)MDIM * KDIM * 2);  // 32 MB

  cvt_bf16_kernel<<<(MDIM * KDIM) / (8 * 256), 256, 0, stream>>>(x, Xbf, MDIM * KDIM);
  transpose_cvt_kernel<<<dim3(NDIM / 64, KDIM / 32), 256, 0, stream>>>(w, Wt);
  gemm_bf16_kernel<<<dim3(NDIM / BN, MDIM / BM), 256, 0, stream>>>(Xbf, Wt, bias, out);
}

// Round 3
// 558.297 us; speedup vs baseline: 1.0874x; 1.0738x over previous
//
#include <hip/hip_runtime.h>

// Dense GEMM: C[M,N] = x[M,K] @ W[K,N] + bias[N], f32 in/out, bf16 MFMA compute.
// R3: BK=64 (halves barrier-drain count, the structural ~20% stall of the
//     2-barrier K-loop), XOR-swizzled 8-chunk LDS rows, fused pre-pass launch.

#define MDIM 8192
#define NDIM 4096
#define KDIM 4096
#define BM 128
#define BN 128
#define BK 64

typedef __bf16 bf16x8 __attribute__((ext_vector_type(8)));
typedef float f32x4 __attribute__((ext_vector_type(4)));
typedef unsigned short u16x8 __attribute__((ext_vector_type(8)));

__device__ __forceinline__ unsigned short f32_to_bf16(float f) {
  union { float f; unsigned int u; } v; v.f = f;
  unsigned int r = 0x7FFFu + ((v.u >> 16) & 1u);  // round-to-nearest-even
  return (unsigned short)((v.u + r) >> 16);
}

// ---- fused pre-pass: blocks [0,16384) convert x; [16384,24576) transpose W
#define CVT_BLOCKS 16384
__global__ __launch_bounds__(256) void prep_kernel(
    const float* __restrict__ x, const float* __restrict__ W,
    unsigned short* __restrict__ Xbf, unsigned short* __restrict__ Wt) {
  const int bid = blockIdx.x;
  if (bid < CVT_BLOCKS) {
    const int i = (bid * 256 + threadIdx.x) * 8;
    float4 a = *(const float4*)(x + i);
    float4 b = *(const float4*)(x + i + 4);
    union { unsigned short s[8]; uint4 v; } o;
    o.s[0] = f32_to_bf16(a.x); o.s[1] = f32_to_bf16(a.y);
    o.s[2] = f32_to_bf16(a.z); o.s[3] = f32_to_bf16(a.w);
    o.s[4] = f32_to_bf16(b.x); o.s[5] = f32_to_bf16(b.y);
    o.s[6] = f32_to_bf16(b.z); o.s[7] = f32_to_bf16(b.w);
    *(uint4*)(Xbf + i) = o.v;
  } else {
    const int tb = bid - CVT_BLOCKS;          // 8192 blocks: 64 n-tiles x 128 k-tiles
    const int n = (tb & 63) * 64 + (threadIdx.x & 63);
    const int kbase = (tb >> 6) * 32 + (threadIdx.x >> 6) * 8;
    u16x8 o;
#pragma unroll
    for (int j = 0; j < 8; j++)
      o[j] = f32_to_bf16(W[(size_t)(kbase + j) * NDIM + n]);
    *(u16x8*)(Wt + (size_t)n * KDIM + kbase) = o;
  }
}

// ---- GEMM: C = A(bf16, MxK) * Bt(bf16, NxK)^T + bias, f32 out ------------
#define GLD_TO_LDS(g, l)                                                      \
  __builtin_amdgcn_global_load_lds(                                           \
      (const __attribute__((address_space(1))) void*)(g),                     \
      (__attribute__((address_space(3))) void*)(l), 16, 0, 0)

__global__ __launch_bounds__(256) void gemm_bf16_kernel(
    const unsigned short* __restrict__ A,   // M x K bf16
    const unsigned short* __restrict__ Bt,  // N x K bf16
    const float* __restrict__ bias,
    float* __restrict__ C) {
  // Rows of 64 bf16 (8 chunks of 16B). Chunk slot s' holds global chunk
  // s = s' ^ (row&7)  -> ds_read_b128 lanes spread 8/bank-group (full rate),
  // and global_load_lds stays lane-contiguous (base + lane*16).
  __shared__ __align__(16) unsigned short As[BM * BK];  // 16 KB
  __shared__ __align__(16) unsigned short Bs[BN * BK];  // 16 KB

  const int tid  = threadIdx.x;
  const int wave = tid >> 6;
  const int lane = tid & 63;
  const int lr   = lane & 15;
  const int quad = lane >> 4;

  const int bm0 = blockIdx.y * BM;
  const int bn0 = blockIdx.x * BN;

  // Staging: wave w stages rows [w*32, w*32+32), 4 instrs x (8 rows x 128B).
  // lane -> row = i*8 + (lane>>3), slot s' = lane&7 -> global chunk s'^(row&7).
  const int stRow = wave * 32 + (lane >> 3);
  const int stSeg = ((lane & 7) ^ ((lane >> 3) & 7)) * 8;  // elements
  const unsigned short* gA0 = A  + (size_t)(bm0 + stRow) * KDIM + stSeg;
  const unsigned short* gA1 = gA0 + 8 * KDIM;
  const unsigned short* gA2 = gA0 + 16 * KDIM;
  const unsigned short* gA3 = gA0 + 24 * KDIM;
  const unsigned short* gB0 = Bt + (size_t)(bn0 + stRow) * KDIM + stSeg;
  const unsigned short* gB1 = gB0 + 8 * KDIM;
  const unsigned short* gB2 = gB0 + 16 * KDIM;
  const unsigned short* gB3 = gB0 + 24 * KDIM;
  unsigned short* lA = As + wave * 2048;   // wave-uniform LDS bases
  unsigned short* lB = Bs + wave * 2048;

  // Wave computes 64x64: 4x4 frags of 16x16x32, two k-halves per BK=64 slab.
  const int wm = (wave >> 1) * 64;
  const int wn = (wave & 1) * 64;
  const int xr = lr & 7;
  // frag (i, half h): addr = (wm+lr)*64 + i*1024 + ((h*4+quad)^xr)*8
  const int slot0 = (quad ^ xr) * 8;            // h=0
  const int slot1 = ((4 + quad) ^ xr) * 8;      // h=1
  const unsigned short* aRow = As + (wm + lr) * BK;
  const unsigned short* bRow = Bs + (wn + lr) * BK;

  f32x4 acc[4][4] = {};

  for (int k0 = 0; k0 < KDIM; k0 += BK) {
    GLD_TO_LDS(gA0, lA);
    GLD_TO_LDS(gA1, lA + 512);
    GLD_TO_LDS(gA2, lA + 1024);
    GLD_TO_LDS(gA3, lA + 1536);
    GLD_TO_LDS(gB0, lB);
    GLD_TO_LDS(gB1, lB + 512);
    GLD_TO_LDS(gB2, lB + 1024);
    GLD_TO_LDS(gB3, lB + 1536);
    gA0 += BK; gA1 += BK; gA2 += BK; gA3 += BK;
    gB0 += BK; gB1 += BK; gB2 += BK; gB3 += BK;
    __syncthreads();

    // half 0 (k = 0..31 of slab)
    {
      bf16x8 af[4], bfv[4];
#pragma unroll
      for (int i = 0; i < 4; i++) {
        af[i]  = *(const bf16x8*)(aRow + i * 16 * BK + slot0);
        bfv[i] = *(const bf16x8*)(bRow + i * 16 * BK + slot0);
      }
#pragma unroll
      for (int mi = 0; mi < 4; mi++)
#pragma unroll
        for (int ni = 0; ni < 4; ni++)
          acc[mi][ni] = __builtin_amdgcn_mfma_f32_16x16x32_bf16(
              af[mi], bfv[ni], acc[mi][ni], 0, 0, 0);
    }
    // half 1 (k = 32..63 of slab)
    {
      bf16x8 af[4], bfv[4];
#pragma unroll
      for (int i = 0; i < 4; i++) {
        af[i]  = *(const bf16x8*)(aRow + i * 16 * BK + slot1);
        bfv[i] = *(const bf16x8*)(bRow + i * 16 * BK + slot1);
      }
#pragma unroll
      for (int mi = 0; mi < 4; mi++)
#pragma unroll
        for (int ni = 0; ni < 4; ni++)
          acc[mi][ni] = __builtin_amdgcn_mfma_f32_16x16x32_bf16(
              af[mi], bfv[ni], acc[mi][ni], 0, 0, 0);
    }
    __syncthreads();
  }

  // Epilogue: C/D layout col = lane&15, row = quad*4 + reg  [m89/m91]
  const int om = bm0 + wm + quad * 4;
  const int on = bn0 + wn + lr;
#pragma unroll
  for (int ni = 0; ni < 4; ni++) {
    float bv = bias[on + ni * 16];
#pragma unroll
    for (int mi = 0; mi < 4; mi++) {
      f32x4 v = acc[mi][ni];
#pragma unroll
      for (int r = 0; r < 4; r++) {
        C[(size_t)(om + mi * 16 + r) * NDIM + (on + ni * 16)] = v[r] + bv;
      }
    }
  }
}

extern "C" void kernel_launch(void* const* d_in, const int* in_sizes, int n_in,
                              void* d_out, int out_size, void* d_ws, size_t ws_size,
                              hipStream_t stream) {
  const float* x    = (const float*)d_in[0];  // 8192 x 4096
  const float* w    = (const float*)d_in[1];  // 4096 x 4096 ([k][n])
  const float* bias = (const float*)d_in[2];  // 4096
  float* out = (float*)d_out;

  unsigned short* Xbf = (unsigned short*)d_ws;  // 64 MB
  unsigned short* Wt  = (unsigned short*)((char*)d_ws + (size_t)MDIM * KDIM * 2);  // 32 MB

  prep_kernel<<<CVT_BLOCKS + 8192, 256, 0, stream>>>(x, w, Xbf, Wt);
  gemm_bf16_kernel<<<dim3(NDIM / BN, MDIM / BM), 256, 0, stream>>>(Xbf, Wt, bias, out);
}